// Round 5
// baseline (597.718 us; speedup 1.0000x reference)
//
#include <hip/hip_runtime.h>
#include <hip/hip_bf16.h>
#include <hip/hip_cooperative_groups.h>

namespace cg = cooperative_groups;

using bf = __bf16;
typedef __attribute__((ext_vector_type(8))) __bf16 bf16x8;
typedef __attribute__((ext_vector_type(4))) float f32x4;

#define MFMA(a, b, c) __builtin_amdgcn_mfma_f32_16x16x32_bf16((a), (b), (c), 0, 0, 0)
#define GLL16(g, s)                                                         \
    __builtin_amdgcn_global_load_lds(                                       \
        (const __attribute__((address_space(1))) void*)(g),                 \
        (__attribute__((address_space(3))) void*)(s), 16, 0, 0)

// ---------------- fp32 -> bf16 convert (8 elems/unit) ----------------
static __device__ __forceinline__ void cvt_one(const float* __restrict__ s,
                                               bf* __restrict__ d, int i)
{
    const f32x4 a = ((const f32x4*)s)[2 * i];
    const f32x4 b = ((const f32x4*)s)[2 * i + 1];
    bf16x8 r;
#pragma unroll
    for (int k = 0; k < 4; ++k) { r[k] = (bf)a[k]; r[4 + k] = (bf)b[k]; }
    ((bf16x8*)d)[i] = r;
}

// ---------------- shared macro set for the 256^2 8-phase GEMM bodies ----------------
#define LOADA(bo, mh, kk)                                                     \
    _Pragma("unroll")                                                         \
    for (int mm = 0; mm < 4; ++mm)                                            \
        a[mm] = *(const bf16x8*)(aBase + (bo) + ((mh) * 4 + mm) * 2048        \
                                 + ((kk) ? skz1 : skz0));
#define LOADB(bo, kk)                                                         \
    _Pragma("unroll")                                                         \
    for (int j = 0; j < 4; ++j)                                               \
        b[j] = *(const bf16x8*)(bBase + (bo) + j * 2048                       \
                                + ((kk) ? skz1 : skz0));
#define PH_OPEN()                                                             \
    __builtin_amdgcn_s_barrier();                                             \
    asm volatile("s_waitcnt lgkmcnt(0)" ::: "memory");                        \
    __builtin_amdgcn_s_setprio(1)
#define MM16(mh)                                                              \
    _Pragma("unroll")                                                         \
    for (int mm = 0; mm < 4; ++mm)                                            \
        _Pragma("unroll")                                                     \
        for (int j = 0; j < 4; ++j)                                           \
            acc[(mh) * 4 + mm][j] = MFMA(a[mm], b[j], acc[(mh) * 4 + mm][j]);
#define PH_CLOSE()                                                            \
    __builtin_amdgcn_s_setprio(0);                                            \
    __builtin_amdgcn_s_barrier()

// ---------------- 256x256 8-phase GEMM body (R3-verified) ----------------
// AF32=0: A bf16 via global_load_lds (R1 winner).  AF32=1: A fp32 reg-staged (R2 verified).
// B bf16 via global_load_lds.  Epilogue: bias + per-64-col-head L2-norm, head-major bf16 out.
template <int GH, int LGR, int AF32>
static __device__ __forceinline__ void gemm256_body(
    const void* __restrict__ Ap, const bf* __restrict__ W,
    const float* __restrict__ bias, bf* __restrict__ C,
    const int bxx, const int byy, const int K)
{
    extern __shared__ __attribute__((aligned(16))) char smem[];
    char* Asm = smem;                // [2 buf][2 half][16384 B]
    char* Bsm = smem + 65536;

    const int tid = threadIdx.x;
    const int lane = tid & 63;
    const int lm = lane & 15;
    const int quad = lane >> 4;
    const int wave = tid >> 6;
    const int wm = wave >> 2;
    const int wn = wave & 3;
    const int row0 = bxx * 256, col0 = byy * 256;
    const int NT = K >> 6;

    const int trow = tid >> 3;
    const int slotL = tid & 7;
    const int sswz = slotL ^ (trow & 7);
    const float* Af = (const float*)Ap + (size_t)(row0 + trow) * K + slotL * 8;
    const bf*    Ab = (const bf*)Ap + (size_t)(row0 + trow) * K + sswz * 8;
    const bf*    Wth = W + (size_t)(col0 + trow) * K + sswz * 8;

    const char* aBase = Asm + wm * 16384 + lm * 128;
    const char* bBase = Bsm + (wn >> 1) * 16384 + ((wn & 1) * 64 + lm) * 128;
    const int skz0 = ((quad ^ (lm & 7)) << 4);
    const int skz1 = (((4 + quad) ^ (lm & 7)) << 4);

    f32x4 acc[8][4] = {};
    f32x4 areg[4][2];

    auto ldA = [&](int kt) {   // AF32 only
#pragma unroll
        for (int hs = 0; hs < 4; ++hs) {
            const float* p = Af + (size_t)((hs >> 1) * 128 + (hs & 1) * 64) * K + kt * 64;
            areg[hs][0] = ((const f32x4*)p)[0];
            areg[hs][1] = ((const f32x4*)p)[1];
        }
    };
    auto wrA = [&](int kt) {   // AF32 only
        const int bo = (kt & 1) * 32768;
#pragma unroll
        for (int hs = 0; hs < 4; ++hs) {
            bf16x8 r;
#pragma unroll
            for (int e = 0; e < 4; ++e) {
                r[e] = (bf)areg[hs][0][e];
                r[4 + e] = (bf)areg[hs][1][e];
            }
            *(bf16x8*)(Asm + bo + (hs >> 1) * 16384 + (hs & 1) * 8192 + trow * 128 + sswz * 16) = r;
        }
    };
    auto stAg = [&](int kt) {  // !AF32 only
        const int bo = (kt & 1) * 32768;
#pragma unroll
        for (int h = 0; h < 2; ++h)
#pragma unroll
            for (int s = 0; s < 2; ++s)
                GLL16(Ab + (size_t)(h * 128 + s * 64) * K + kt * 64,
                      Asm + bo + h * 16384 + s * 8192 + tid * 16);
    };
    auto stB = [&](int kt) {
        const int bo = (kt & 1) * 32768;
#pragma unroll
        for (int h = 0; h < 2; ++h)
#pragma unroll
            for (int s = 0; s < 2; ++s)
                GLL16(Wth + (size_t)(h * 128 + s * 64) * K + kt * 64,
                      Bsm + bo + h * 16384 + s * 8192 + tid * 16);
    };

    // prologue
    if (AF32) {
        stB(0); ldA(0); stB(1);
        asm volatile("s_waitcnt vmcnt(4)" ::: "memory");
        wrA(0);
        asm volatile("s_waitcnt lgkmcnt(0)" ::: "memory");
    } else {
        stB(0); stAg(0); stB(1);
        asm volatile("s_waitcnt vmcnt(4)" ::: "memory");
    }
    __builtin_amdgcn_s_barrier();

    for (int it = 0; it < NT; it += 2) {
        const int more = (it + 2 < NT);
        bf16x8 a[4], b[4];

        // ---- tile it (buf0) ----
        LOADA(0, 0, 0) LOADB(0, 0)
        if (AF32) ldA(it + 1); else stAg(it + 1);
        PH_OPEN(); MM16(0) PH_CLOSE();

        LOADA(0, 1, 0)
        PH_OPEN(); MM16(1) PH_CLOSE();

        LOADA(0, 0, 1) LOADB(0, 1)
        PH_OPEN(); MM16(0) PH_CLOSE();

        LOADA(0, 1, 1) if (more) stB(it + 2);
        PH_OPEN(); MM16(1)
        __builtin_amdgcn_s_setprio(0);
        if (more) { asm volatile("s_waitcnt vmcnt(4)" ::: "memory"); }
        else      { asm volatile("s_waitcnt vmcnt(0)" ::: "memory"); }
        if (AF32) {
            wrA(it + 1);
            asm volatile("s_waitcnt lgkmcnt(0)" ::: "memory");
        }
        __builtin_amdgcn_s_barrier();

        // ---- tile it+1 (buf1) ----
        LOADA(32768, 0, 0) LOADB(32768, 0)
        if (more) { if (AF32) ldA(it + 2); else stAg(it + 2); }
        PH_OPEN(); MM16(0) PH_CLOSE();

        LOADA(32768, 1, 0)
        PH_OPEN(); MM16(1) PH_CLOSE();

        LOADA(32768, 0, 1) LOADB(32768, 1)
        PH_OPEN(); MM16(0) PH_CLOSE();

        LOADA(32768, 1, 1) if (more) stB(it + 3);
        PH_OPEN(); MM16(1)
        __builtin_amdgcn_s_setprio(0);
        if (more) {
            asm volatile("s_waitcnt vmcnt(4)" ::: "memory");
            if (AF32) {
                wrA(it + 2);
                asm volatile("s_waitcnt lgkmcnt(0)" ::: "memory");
            }
        }
        __builtin_amdgcn_s_barrier();
    }

    // ---- epilogue: bias + L2-norm per 64-col head, head-major bf16 out ----
    float bv[4];
#pragma unroll
    for (int j = 0; j < 4; ++j) bv[j] = bias[col0 + wn * 64 + j * 16 + lm];
    const int g = (col0 + wn * 64) >> 6;
#pragma unroll
    for (int m = 0; m < 8; ++m) {
#pragma unroll
        for (int rg = 0; rg < 4; ++rg) {
            float v[4];
            float ss = 0.f;
#pragma unroll
            for (int j = 0; j < 4; ++j) {
                const float x = acc[m][j][rg] + bv[j];
                v[j] = x;
                ss += x * x;
            }
            ss += __shfl_xor(ss, 1, 64);
            ss += __shfl_xor(ss, 2, 64);
            ss += __shfl_xor(ss, 4, 64);
            ss += __shfl_xor(ss, 8, 64);
            const float inv = 1.0f / fmaxf(sqrtf(ss), 1e-12f);
            const int row = row0 + wm * 128 + m * 16 + quad * 4 + rg;
            const int bt = row >> LGR;
            const int rl = row & ((1 << LGR) - 1);
            bf* Cr = C + (((size_t)(bt * GH + g) << LGR) + rl) * 64;
#pragma unroll
            for (int j = 0; j < 4; ++j)
                Cr[j * 16 + lm] = (bf)(v[j] * inv);
        }
    }
}

// ---------------- 256x256 output-projection body: A=X bf16 GLL, B=Wm fp32 staged ----------------
// 4-phase/tile, dbuf, drain-0 at tile boundaries.  EPI: bias + fp32 residual, fp32 row-major out.
static __device__ __forceinline__ void gemm256_out_body(
    const bf* __restrict__ Xin, const float* __restrict__ Wm,
    const float* __restrict__ bm, const float* __restrict__ res,
    float* __restrict__ out, const int bxx, const int byy)
{
    extern __shared__ __attribute__((aligned(16))) char smem[];
    char* Asm = smem;
    char* Bsm = smem + 65536;
    const int K = 512, N = 512, NT = 8;

    const int tid = threadIdx.x;
    const int lane = tid & 63;
    const int lm = lane & 15;
    const int quad = lane >> 4;
    const int wave = tid >> 6;
    const int wm = wave >> 2;
    const int wn = wave & 3;
    const int row0 = bxx * 256, col0 = byy * 256;

    const int trow = tid >> 3;
    const int slotL = tid & 7;
    const int sswz = slotL ^ (trow & 7);
    const bf* Ab = Xin + (size_t)(row0 + trow) * K + sswz * 8;
    const float* Wf = Wm + (size_t)(col0 + trow) * K + slotL * 8;

    const char* aBase = Asm + wm * 16384 + lm * 128;
    const char* bBase = Bsm + (wn >> 1) * 16384 + ((wn & 1) * 64 + lm) * 128;
    const int skz0 = ((quad ^ (lm & 7)) << 4);
    const int skz1 = (((4 + quad) ^ (lm & 7)) << 4);

    f32x4 acc[8][4] = {};
    f32x4 breg[4][2];

    auto stA = [&](int kt) {
        const int bo = (kt & 1) * 32768;
#pragma unroll
        for (int h = 0; h < 2; ++h)
#pragma unroll
            for (int s = 0; s < 2; ++s)
                GLL16(Ab + (size_t)(h * 128 + s * 64) * K + kt * 64,
                      Asm + bo + h * 16384 + s * 8192 + tid * 16);
    };
    auto ldB = [&](int kt) {
#pragma unroll
        for (int hs = 0; hs < 4; ++hs) {
            const float* p = Wf + (size_t)((hs >> 1) * 128 + (hs & 1) * 64) * K + kt * 64;
            breg[hs][0] = ((const f32x4*)p)[0];
            breg[hs][1] = ((const f32x4*)p)[1];
        }
    };
    auto wrB = [&](int kt) {
        const int bo = (kt & 1) * 32768;
#pragma unroll
        for (int hs = 0; hs < 4; ++hs) {
            bf16x8 r;
#pragma unroll
            for (int e = 0; e < 4; ++e) {
                r[e] = (bf)breg[hs][0][e];
                r[4 + e] = (bf)breg[hs][1][e];
            }
            *(bf16x8*)(Bsm + bo + (hs >> 1) * 16384 + (hs & 1) * 8192 + trow * 128 + sswz * 16) = r;
        }
    };

    // prologue: tile 0 into buf0
    stA(0); ldB(0);
    asm volatile("s_waitcnt vmcnt(0)" ::: "memory");
    wrB(0);
    asm volatile("s_waitcnt lgkmcnt(0)" ::: "memory");
    __builtin_amdgcn_s_barrier();

    for (int it = 0; it < NT; ++it) {
        const int more = (it + 1 < NT);
        const int bo = (it & 1) * 32768;
        bf16x8 a[4], b[4];

        LOADA(bo, 0, 0) LOADB(bo, 0)
        if (more) { stA(it + 1); ldB(it + 1); }
        PH_OPEN(); MM16(0) PH_CLOSE();

        LOADA(bo, 1, 0)
        PH_OPEN(); MM16(1) PH_CLOSE();

        LOADA(bo, 0, 1) LOADB(bo, 1)
        PH_OPEN(); MM16(0) PH_CLOSE();

        LOADA(bo, 1, 1)
        PH_OPEN(); MM16(1)
        __builtin_amdgcn_s_setprio(0);
        if (more) {
            asm volatile("s_waitcnt vmcnt(0)" ::: "memory");
            wrB(it + 1);
            asm volatile("s_waitcnt lgkmcnt(0)" ::: "memory");
        }
        __builtin_amdgcn_s_barrier();
    }

    // ---- epilogue: bias + fp32 residual, row-major fp32 ----
    float bv[4];
#pragma unroll
    for (int j = 0; j < 4; ++j) bv[j] = bm[col0 + wn * 64 + j * 16 + lm];
#pragma unroll
    for (int m = 0; m < 8; ++m) {
#pragma unroll
        for (int rg = 0; rg < 4; ++rg) {
            const int row = row0 + wm * 128 + m * 16 + quad * 4 + rg;
#pragma unroll
            for (int j = 0; j < 4; ++j) {
                const size_t idx = (size_t)row * N + col0 + wn * 64 + j * 16 + lm;
                out[idx] = acc[m][j][rg] + bv[j] + res[idx];
            }
        }
    }
}

// ---------------- flash-style cosine attention unit (256-thread half-block) ----------------
static __device__ __forceinline__ void attn_unit(
    const bf* __restrict__ qn, const bf* __restrict__ kvn, bf* __restrict__ X,
    const int u, char* __restrict__ sm, const int tid)
{
    bf* Kt = (bf*)sm;                 // [128][72]  = 18432 B
    bf* Vt = (bf*)(sm + 18432);       // [64][136]  = 17408 B
    bf* Ps = (bf*)(sm + 35840);       // [4][16*40] =  5120 B

    const int qb = u >> 9;
    const int rb = u & 511;
    const int bt = rb >> 3;
    const int h = rb & 7;
    const int lane = tid & 63;
    const int wave = tid >> 6;
    const int lm = lane & 15;
    const int quad = lane >> 4;

    const bf* qh = qn + ((size_t)(bt * 8 + h) * 256 + qb * 128) * 64;
    const bf* kh = kvn + (size_t)(bt * 16 + h) * 512 * 64;
    const bf* vh = kvn + (size_t)(bt * 16 + 8 + h) * 512 * 64;

    const int srow = tid >> 1;
    const int sseg = (tid & 1) * 32;

    f32x4 o[2][4] = {};
    float sum[2][4] = {};
    bf* Pw = Ps + wave * 640;

    for (int t = 0; t < 4; ++t) {
        {
            const bf* kr = kh + (size_t)(t * 128 + srow) * 64 + sseg;
            bf* kd = Kt + srow * 72 + sseg;
#pragma unroll
            for (int j = 0; j < 4; ++j)
                *(bf16x8*)(kd + j * 8) = *(const bf16x8*)(kr + j * 8);

            const bf* vr = vh + (size_t)(t * 128 + srow) * 64 + sseg;
            bf16x8 vv[4];
#pragma unroll
            for (int j = 0; j < 4; ++j) vv[j] = *(const bf16x8*)(vr + j * 8);
#pragma unroll
            for (int j = 0; j < 4; ++j)
#pragma unroll
                for (int e = 0; e < 8; ++e)
                    Vt[(sseg + j * 8 + e) * 136 + srow] = vv[j][e];
        }
        __syncthreads();

#pragma unroll
        for (int c = 0; c < 2; ++c) {
            const int r0 = wave * 32 + c * 16;
            const bf* qp = qh + (size_t)(r0 + lm) * 64 + quad * 8;
            const bf16x8 a0 = *(const bf16x8*)qp;
            const bf16x8 a1 = *(const bf16x8*)(qp + 32);

            f32x4 s[8];
#pragma unroll
            for (int nt = 0; nt < 8; ++nt) {
                const bf16x8 k0 = *(const bf16x8*)(&Kt[(nt * 16 + lm) * 72 + quad * 8]);
                const bf16x8 k1 = *(const bf16x8*)(&Kt[(nt * 16 + lm) * 72 + 32 + quad * 8]);
                f32x4 z = {};
                z = MFMA(a0, k0, z);
                s[nt] = MFMA(a1, k1, z);
            }

            for (int ntp = 0; ntp < 4; ++ntp) {
#pragma unroll
                for (int tt = 0; tt < 2; ++tt)
#pragma unroll
                    for (int rr = 0; rr < 4; ++rr) {
                        const float e = __expf(s[ntp * 2 + tt][rr] * 0.125f);
                        sum[c][rr] += e;
                        Pw[(quad * 4 + rr) * 40 + tt * 16 + lm] = (bf)e;
                    }
                const bf16x8 ap = *(const bf16x8*)(&Pw[lm * 40 + quad * 8]);
#pragma unroll
                for (int dt = 0; dt < 4; ++dt) {
                    const bf16x8 bv = *(const bf16x8*)(&Vt[(dt * 16 + lm) * 136 + ntp * 32 + quad * 8]);
                    o[c][dt] = MFMA(ap, bv, o[c][dt]);
                }
            }
        }
        __syncthreads();
    }

#pragma unroll
    for (int c = 0; c < 2; ++c) {
        float inv[4];
#pragma unroll
        for (int rr = 0; rr < 4; ++rr) {
            float sm2 = sum[c][rr];
            sm2 += __shfl_xor(sm2, 1, 64);
            sm2 += __shfl_xor(sm2, 2, 64);
            sm2 += __shfl_xor(sm2, 4, 64);
            sm2 += __shfl_xor(sm2, 8, 64);
            inv[rr] = 1.0f / sm2;
        }
        bf* Xp = X + ((size_t)bt * 256 + qb * 128 + wave * 32 + c * 16) * 512 + h * 64;
#pragma unroll
        for (int dt = 0; dt < 4; ++dt)
#pragma unroll
            for (int rr = 0; rr < 4; ++rr)
                Xp[(size_t)(quad * 4 + rr) * 512 + dt * 16 + lm] = (bf)(o[c][dt][rr] * inv[rr]);
    }
}

// ---------------- the single cooperative persistent kernel ----------------
// 256 blocks x 512 threads, 128 KiB dynamic LDS -> exactly 1 block/CU.
__global__ __launch_bounds__(512, 2) void mega(
    const float* __restrict__ q, const float* __restrict__ kv,
    const float* __restrict__ Wq, const float* __restrict__ bq,
    const float* __restrict__ Wkv, const float* __restrict__ bkv,
    const float* __restrict__ Wm, const float* __restrict__ bm,
    float* __restrict__ out,
    bf* __restrict__ kvb, bf* __restrict__ kvn, bf* __restrict__ X,
    bf* __restrict__ qn, bf* __restrict__ wkvb, bf* __restrict__ wqb,
    unsigned* __restrict__ ctr)
{
    cg::grid_group grid = cg::this_grid();
    const int bid = blockIdx.x;
    const int tid = threadIdx.x;

    // ---- stage 1: fp32->bf16 converts: kv (2097152 u) + Wkv (65536) + Wq (32768) ----
    if (bid == 0 && tid == 0) *ctr = 0u;
    {
        const int idx = bid * 512 + tid;
        for (int u = idx; u < 2195456; u += 131072) {
            if (u < 2097152)       cvt_one(kv, kvb, u);
            else if (u < 2162688)  cvt_one(Wkv, wkvb, u - 2097152);
            else                   cvt_one(Wq, wqb, u - 2162688);
        }
    }
    __threadfence();
    grid.sync();

    // ---- stage 2: 640 GEMM tile-jobs via atomic queue ----
    // jobs 0..127   : Q-proj  (A = q fp32 reg-staged, B = wqb GLL)  [long poles, issued first]
    // jobs 128..639 : KV-proj (A = kvb bf16 GLL, B = wkvb GLL)       [R1-verified path]
    {
        __shared__ int sjob;
        for (;;) {
            __syncthreads();
            if (tid == 0) sjob = (int)atomicAdd(ctr, 1u);
            __syncthreads();
            const int j = sjob;
            if (j >= 640) break;
            if (j < 128)
                gemm256_body<8, 8, 1>((const void*)q, wqb, bq, qn, j & 63, j >> 6, 512);
            else {
                const int k = j - 128;
                gemm256_body<16, 9, 0>((const void*)kvb, wkvb, bkv, kvn, k & 127, k >> 7, 512);
            }
        }
    }
    __threadfence();
    grid.sync();

    // ---- stage 3: attention, 1024 units = 256 blocks x 2 halves x 2 rounds ----
    {
        extern __shared__ __attribute__((aligned(16))) char smem[];
        const int tid2 = tid & 255;
        const int half = tid >> 8;
        char* sm = smem + half * 40960;
        attn_unit(qn, kvn, X, (bid << 1) | half, sm, tid2);
        attn_unit(qn, kvn, X, 512 + ((bid << 1) | half), sm, tid2);
    }
    __threadfence();
    grid.sync();

    // ---- stage 4: output projection, 128 jobs on blocks 0..127 ----
    if (bid < 128)
        gemm256_out_body(X, Wm, bm, q, out, bid & 63, bid >> 6);
}

#undef LOADA
#undef LOADB
#undef PH_OPEN
#undef MM16
#undef PH_CLOSE

extern "C" void kernel_launch(void* const* d_in, const int* in_sizes, int n_in,
                              void* d_out, int out_size, void* d_ws, size_t ws_size,
                              hipStream_t stream)
{
    const float* q   = (const float*)d_in[0];  // (8,8,256,512) fp32
    const float* kv  = (const float*)d_in[1];  // (8,8,512,512) fp32
    const float* Wq  = (const float*)d_in[2];
    const float* bq  = (const float*)d_in[3];
    const float* Wkv = (const float*)d_in[4];
    const float* bkv = (const float*)d_in[5];
    const float* Wm  = (const float*)d_in[6];
    const float* bm  = (const float*)d_in[7];
    float* out = (float*)d_out;

    // ws (max 96 MiB, proven):
    //   kvb [0,32)  stage1->2      kvn [32,96)  stage2->3      X [0,16) stage3->4 (kvb dead)
    // d_out (32 MiB):
    //   qn [0,16) stage2->3;  wkvb [16,17), wqb [17,17.5) stage1->2;  ctr @18 MiB stage1->2
    //   all dead before stage 4 rewrites d_out with fp32 out.
    char* ws = (char*)d_ws;
    bf* kvb = (bf*)ws;
    bf* kvn = (bf*)(ws + ((size_t)32 << 20));
    bf* X   = (bf*)ws;
    char* dob = (char*)d_out;
    bf* qn   = (bf*)dob;
    bf* wkvb = (bf*)(dob + ((size_t)16 << 20));
    bf* wqb  = (bf*)(dob + ((size_t)17 << 20));
    unsigned* ctr = (unsigned*)(dob + ((size_t)18 << 20));

    (void)hipFuncSetAttribute((const void*)mega,
                              hipFuncAttributeMaxDynamicSharedMemorySize, 131072);

    void* args[] = { (void*)&q, (void*)&kv, (void*)&Wq, (void*)&bq,
                     (void*)&Wkv, (void*)&bkv, (void*)&Wm, (void*)&bm,
                     (void*)&out, (void*)&kvb, (void*)&kvn, (void*)&X,
                     (void*)&qn, (void*)&wkvb, (void*)&wqb, (void*)&ctr };
    (void)hipLaunchCooperativeKernel((const void*)mega, dim3(256), dim3(512),
                                     args, 131072, stream);
}

// Round 6
// 294.697 us; speedup vs baseline: 2.0282x; 2.0282x over previous
//
#include <hip/hip_runtime.h>
#include <hip/hip_bf16.h>

using bf = __bf16;
typedef __attribute__((ext_vector_type(8))) __bf16 bf16x8;
typedef __attribute__((ext_vector_type(4))) float f32x4;

#define MFMA(a, b, c) __builtin_amdgcn_mfma_f32_16x16x32_bf16((a), (b), (c), 0, 0, 0)
#define GLL16(g, s)                                                         \
    __builtin_amdgcn_global_load_lds(                                       \
        (const __attribute__((address_space(1))) void*)(g),                 \
        (__attribute__((address_space(3))) void*)(s), 16, 0, 0)

// ---------------- fp32 -> bf16 convert (8 elems/unit) ----------------
static __device__ __forceinline__ void cvt_one(const float* __restrict__ s,
                                               bf* __restrict__ d, int i)
{
    const f32x4 a = ((const f32x4*)s)[2 * i];
    const f32x4 b = ((const f32x4*)s)[2 * i + 1];
    bf16x8 r;
#pragma unroll
    for (int k = 0; k < 4; ++k) { r[k] = (bf)a[k]; r[4 + k] = (bf)b[k]; }
    ((bf16x8*)d)[i] = r;
}

__global__ __launch_bounds__(256) void cvt2(const float* __restrict__ s1, bf* __restrict__ d1, int n1,
                                            const float* __restrict__ s2, bf* __restrict__ d2, int n2)
{
    int i = blockIdx.x * 256 + threadIdx.x;
    if (i < n1) { cvt_one(s1, d1, i); return; }
    i -= n1;
    if (i < n2) cvt_one(s2, d2, i);
}

// ---------------- m97-style 128x128 bf16 GEMM body ----------------
// AF32/BF32: operand fp32, converted to bf16 during LDS staging (reg-stage + ds_write);
//            identical layout/rounding to cvt+global_load_lds.  [R4-verified]
// EPI 0: bias + L2-norm per 64-col head group, bf16 head-major out.
// EPI 1: bias + fp32 residual, fp32 out row-major.
template <int EPI, int GH, int LGR, int AF32, int BF32>
static __device__ __forceinline__ void gemm128_body(
    const void* __restrict__ Ap, const void* __restrict__ Wp,
    const float* __restrict__ bias, const float* __restrict__ res,
    void* __restrict__ Cout, int bx, int by, int N, int K)
{
    __shared__ __attribute__((aligned(16))) bf As[128 * 32];
    __shared__ __attribute__((aligned(16))) bf Bs[128 * 32];

    const int lane = threadIdx.x & 63;
    const int wave = threadIdx.x >> 6;
    const int lm = lane & 15;
    const int quad = lane >> 4;
    const int row0 = bx * 128, col0 = by * 128;
    const int wrow = (wave >> 1) * 64, wcol = (wave & 1) * 64;

    const int sr = lane >> 2;            // 0..15
    const int sc = (lane & 3) * 8;       // elem offset 0,8,16,24
    const bf* Ag = nullptr; const float* Agf = nullptr;
    if (AF32) Agf = (const float*)Ap + (size_t)(row0 + wave * 32 + sr) * K + sc;
    else      Ag  = (const bf*)Ap + (size_t)(row0 + wave * 32 + sr) * K + sc;
    const bf* Wg = nullptr; const float* Wgf = nullptr;
    if (BF32) Wgf = (const float*)Wp + (size_t)(col0 + wave * 32 + sr) * K + sc;
    else      Wg  = (const bf*)Wp + (size_t)(col0 + wave * 32 + sr) * K + sc;
    bf* AsW = As + wave * 1024;
    bf* BsW = Bs + wave * 1024;

    f32x4 acc[4][4] = {};

    for (int k0 = 0; k0 < K; k0 += 32) {
        if (AF32) {
            f32x4 u0 = *(const f32x4*)(Agf + k0);
            f32x4 u1 = *(const f32x4*)(Agf + k0 + 4);
            f32x4 u2 = *(const f32x4*)(Agf + (size_t)16 * K + k0);
            f32x4 u3 = *(const f32x4*)(Agf + (size_t)16 * K + k0 + 4);
            bf16x8 r0, r1;
#pragma unroll
            for (int e = 0; e < 4; ++e) {
                r0[e] = (bf)u0[e]; r0[4 + e] = (bf)u1[e];
                r1[e] = (bf)u2[e]; r1[4 + e] = (bf)u3[e];
            }
            *(bf16x8*)(AsW + lane * 8) = r0;
            *(bf16x8*)(AsW + 512 + lane * 8) = r1;
        } else {
            GLL16(Ag + k0, AsW);
            GLL16(Ag + (size_t)16 * K + k0, AsW + 512);
        }
        if (BF32) {
            f32x4 w0 = *(const f32x4*)(Wgf + k0);
            f32x4 w1 = *(const f32x4*)(Wgf + k0 + 4);
            f32x4 w2 = *(const f32x4*)(Wgf + (size_t)16 * K + k0);
            f32x4 w3 = *(const f32x4*)(Wgf + (size_t)16 * K + k0 + 4);
            bf16x8 s0, s1;
#pragma unroll
            for (int e = 0; e < 4; ++e) {
                s0[e] = (bf)w0[e]; s0[4 + e] = (bf)w1[e];
                s1[e] = (bf)w2[e]; s1[4 + e] = (bf)w3[e];
            }
            *(bf16x8*)(BsW + lane * 8) = s0;
            *(bf16x8*)(BsW + 512 + lane * 8) = s1;
        } else {
            GLL16(Wg + k0, BsW);
            GLL16(Wg + (size_t)16 * K + k0, BsW + 512);
        }
        __syncthreads();

        bf16x8 a[4], b[4];
#pragma unroll
        for (int i = 0; i < 4; ++i)
            a[i] = *(const bf16x8*)(As + (wrow + i * 16 + lm) * 32 + quad * 8);
#pragma unroll
        for (int j = 0; j < 4; ++j)
            b[j] = *(const bf16x8*)(Bs + (wcol + j * 16 + lm) * 32 + quad * 8);
#pragma unroll
        for (int i = 0; i < 4; ++i)
#pragma unroll
            for (int j = 0; j < 4; ++j)
                acc[i][j] = MFMA(a[i], b[j], acc[i][j]);
        __syncthreads();
    }

    float bv[4];
#pragma unroll
    for (int j = 0; j < 4; ++j) bv[j] = bias[col0 + wcol + j * 16 + lm];

    if (EPI == 0) {
        bf* C = (bf*)Cout;
        const int g = (col0 + wcol) >> 6;
#pragma unroll
        for (int i = 0; i < 4; ++i) {
#pragma unroll
            for (int rg = 0; rg < 4; ++rg) {
                float v[4];
                float ss = 0.f;
#pragma unroll
                for (int j = 0; j < 4; ++j) {
                    const float x = acc[i][j][rg] + bv[j];
                    v[j] = x;
                    ss += x * x;
                }
                ss += __shfl_xor(ss, 1, 64);
                ss += __shfl_xor(ss, 2, 64);
                ss += __shfl_xor(ss, 4, 64);
                ss += __shfl_xor(ss, 8, 64);
                const float inv = 1.0f / fmaxf(sqrtf(ss), 1e-12f);
                const int row = row0 + wrow + i * 16 + quad * 4 + rg;
                const int bt = row >> LGR;
                const int rl = row & ((1 << LGR) - 1);
                bf* Cr = C + (((size_t)(bt * GH + g) << LGR) + rl) * 64;
#pragma unroll
                for (int j = 0; j < 4; ++j)
                    Cr[j * 16 + lm] = (bf)(v[j] * inv);
            }
        }
    } else {
        float* C = (float*)Cout;
#pragma unroll
        for (int i = 0; i < 4; ++i) {
#pragma unroll
            for (int rg = 0; rg < 4; ++rg) {
                const int row = row0 + wrow + i * 16 + quad * 4 + rg;
#pragma unroll
                for (int j = 0; j < 4; ++j) {
                    const size_t idx = (size_t)row * N + col0 + wcol + j * 16 + lm;
                    C[idx] = acc[i][j][rg] + bv[j] + res[idx];
                }
            }
        }
    }
}

// Q projection: A = q fp32, B = Wq fp32, both staged-convert.  No cvt pass needed.
__global__ __launch_bounds__(256) void qproj(
    const float* __restrict__ q, const float* __restrict__ Wq,
    const float* __restrict__ bq, bf* __restrict__ qn)
{
    gemm128_body<0, 8, 8, 1, 1>(q, Wq, bq, nullptr, qn, blockIdx.x, blockIdx.y, 512, 512);
}

// Output projection: A = X bf16 (GLL), B = Wm fp32 staged-convert, fp32 residual epilogue.
__global__ __launch_bounds__(256) void outproj(
    const bf* __restrict__ X, const float* __restrict__ Wm,
    const float* __restrict__ bm, const float* __restrict__ q,
    float* __restrict__ out)
{
    gemm128_body<1, 0, 0, 0, 1>(X, Wm, bm, q, out, blockIdx.x, blockIdx.y, 512, 512);
}

// ---------------- 256x256 8-phase bf16 GEMM (exact R1 shape: standalone template, 2D grid) ----
// A bf16 + B bf16 via global_load_lds, pre-swizzled sources.  [R1-measured 56.4 us @ KV shape]
// Epilogue: bias + per-64-col-head L2-norm, bf16 head-major out.
template <int GH, int LGR>
__global__ __launch_bounds__(512, 2) void gemm256(
    const bf* __restrict__ A, const bf* __restrict__ W,
    const float* __restrict__ bias, bf* __restrict__ C,
    int M, int N, int K)
{
    extern __shared__ __attribute__((aligned(16))) char smem[];
    char* Asm = smem;                // [2 buf][2 half][16384 B]
    char* Bsm = smem + 65536;

    const int tid = threadIdx.x;
    const int lane = tid & 63;
    const int lm = lane & 15;
    const int quad = lane >> 4;
    const int wave = tid >> 6;
    const int wm = wave >> 2;        // 0..1  (A half)
    const int wn = wave & 3;         // 0..3
    const int row0 = blockIdx.x * 256, col0 = blockIdx.y * 256;
    const int NT = K >> 6;           // K multiple of 128

    // staging: thread t covers row (t>>3), phys slot (t&7); source slot pre-swizzled
    const int trow = tid >> 3;
    const int tslot = (tid & 7) ^ (trow & 7);
    const bf* Ath = A + (size_t)(row0 + trow) * K + tslot * 8;
    const bf* Wth = W + (size_t)(col0 + trow) * K + tslot * 8;

    // compute-side read bases + swizzled k-slot offsets
    const char* aBase = Asm + wm * 16384 + lm * 128;
    const char* bBase = Bsm + (wn >> 1) * 16384 + ((wn & 1) * 64 + lm) * 128;
    const int skz0 = ((quad ^ (lm & 7)) << 4);
    const int skz1 = (((4 + quad) ^ (lm & 7)) << 4);

    f32x4 acc[8][4] = {};

    auto stA = [&](int kt) {
        const int bo = (kt & 1) * 32768;
#pragma unroll
        for (int h = 0; h < 2; ++h)
#pragma unroll
            for (int s = 0; s < 2; ++s)
                GLL16(Ath + (size_t)(h * 128 + s * 64) * K + kt * 64,
                      Asm + bo + h * 16384 + s * 8192 + tid * 16);
    };
    auto stB = [&](int kt) {
        const int bo = (kt & 1) * 32768;
#pragma unroll
        for (int h = 0; h < 2; ++h)
#pragma unroll
            for (int s = 0; s < 2; ++s)
                GLL16(Wth + (size_t)(h * 128 + s * 64) * K + kt * 64,
                      Bsm + bo + h * 16384 + s * 8192 + tid * 16);
    };

#define LOADA(bo, mh, kk)                                                     \
    _Pragma("unroll")                                                         \
    for (int mm = 0; mm < 4; ++mm)                                            \
        a[mm] = *(const bf16x8*)(aBase + (bo) + ((mh) * 4 + mm) * 2048        \
                                 + ((kk) ? skz1 : skz0));
#define LOADB(bo, kk)                                                         \
    _Pragma("unroll")                                                         \
    for (int j = 0; j < 4; ++j)                                               \
        b[j] = *(const bf16x8*)(bBase + (bo) + j * 2048                       \
                                + ((kk) ? skz1 : skz0));
#define PH_OPEN()                                                             \
    __builtin_amdgcn_s_barrier();                                             \
    asm volatile("s_waitcnt lgkmcnt(0)" ::: "memory");                        \
    __builtin_amdgcn_s_setprio(1)
#define MM16(mh)                                                              \
    _Pragma("unroll")                                                         \
    for (int mm = 0; mm < 4; ++mm)                                            \
        _Pragma("unroll")                                                     \
        for (int j = 0; j < 4; ++j)                                           \
            acc[(mh) * 4 + mm][j] = MFMA(a[mm], b[j], acc[(mh) * 4 + mm][j]);
#define PH_CLOSE()                                                            \
    __builtin_amdgcn_s_setprio(0);                                            \
    __builtin_amdgcn_s_barrier()

    // prologue: stage B0, A0, B1; wait for tile0 (B1 may stay in flight)
    stB(0); stA(0); stB(1);
    asm volatile("s_waitcnt vmcnt(4)" ::: "memory");
    __builtin_amdgcn_s_barrier();

    for (int it = 0; it < NT; it += 2) {
        const int more = (it + 2 < NT);
        bf16x8 a[4], b[4];

        // ---- tile it (buf0) ----
        LOADA(0, 0, 0) LOADB(0, 0) stA(it + 1);
        PH_OPEN(); MM16(0) PH_CLOSE();

        LOADA(0, 1, 0)
        PH_OPEN(); MM16(1) PH_CLOSE();

        LOADA(0, 0, 1) LOADB(0, 1)
        PH_OPEN(); MM16(0) PH_CLOSE();

        LOADA(0, 1, 1) if (more) stB(it + 2);
        PH_OPEN(); MM16(1)
        __builtin_amdgcn_s_setprio(0);
        if (more) { asm volatile("s_waitcnt vmcnt(4)" ::: "memory"); }
        else      { asm volatile("s_waitcnt vmcnt(0)" ::: "memory"); }
        __builtin_amdgcn_s_barrier();

        // ---- tile it+1 (buf1) ----
        LOADA(32768, 0, 0) LOADB(32768, 0) if (more) stA(it + 2);
        PH_OPEN(); MM16(0) PH_CLOSE();

        LOADA(32768, 1, 0)
        PH_OPEN(); MM16(1) PH_CLOSE();

        LOADA(32768, 0, 1) LOADB(32768, 1)
        PH_OPEN(); MM16(0) PH_CLOSE();

        LOADA(32768, 1, 1) if (more) stB(it + 3);
        PH_OPEN(); MM16(1)
        __builtin_amdgcn_s_setprio(0);
        if (more) { asm volatile("s_waitcnt vmcnt(4)" ::: "memory"); }
        __builtin_amdgcn_s_barrier();
    }
#undef LOADA
#undef LOADB
#undef PH_OPEN
#undef MM16
#undef PH_CLOSE

    // ---- epilogue: bias + L2-norm per 64-col head, head-major bf16 out ----
    float bv[4];
#pragma unroll
    for (int j = 0; j < 4; ++j) bv[j] = bias[col0 + wn * 64 + j * 16 + lm];
    const int g = (col0 + wn * 64) >> 6;
#pragma unroll
    for (int m = 0; m < 8; ++m) {
#pragma unroll
        for (int rg = 0; rg < 4; ++rg) {
            float v[4];
            float ss = 0.f;
#pragma unroll
            for (int j = 0; j < 4; ++j) {
                const float x = acc[m][j][rg] + bv[j];
                v[j] = x;
                ss += x * x;
            }
            ss += __shfl_xor(ss, 1, 64);
            ss += __shfl_xor(ss, 2, 64);
            ss += __shfl_xor(ss, 4, 64);
            ss += __shfl_xor(ss, 8, 64);
            const float inv = 1.0f / fmaxf(sqrtf(ss), 1e-12f);
            const int row = row0 + wm * 128 + m * 16 + quad * 4 + rg;
            const int bt = row >> LGR;
            const int rl = row & ((1 << LGR) - 1);
            bf* Cr = C + (((size_t)(bt * GH + g) << LGR) + rl) * 64;
#pragma unroll
            for (int j = 0; j < 4; ++j)
                Cr[j * 16 + lm] = (bf)(v[j] * inv);
        }
    }
}

// ---------------- flash-style cosine attention, NO-MAX softmax (verified) ----------------
__global__ __launch_bounds__(256, 4) void attn(
    const bf* __restrict__ qn, const bf* __restrict__ kvn, bf* __restrict__ X)
{
    __shared__ __attribute__((aligned(16))) bf Kt[128 * 72];
    __shared__ __attribute__((aligned(16))) bf Vt[64 * 136];
    __shared__ __attribute__((aligned(16))) bf Ps[4][16 * 40];

    const int qb = blockIdx.x >> 9;
    const int rb = blockIdx.x & 511;
    const int bt = rb >> 3;
    const int h = rb & 7;
    const int tid = threadIdx.x;
    const int lane = tid & 63;
    const int wave = tid >> 6;
    const int lm = lane & 15;
    const int quad = lane >> 4;

    const bf* qh = qn + ((size_t)(bt * 8 + h) * 256 + qb * 128) * 64;
    const bf* kh = kvn + (size_t)(bt * 16 + h) * 512 * 64;
    const bf* vh = kvn + (size_t)(bt * 16 + 8 + h) * 512 * 64;

    const int srow = tid >> 1;
    const int sseg = (tid & 1) * 32;

    f32x4 o[2][4] = {};
    float sum[2][4] = {};
    bf* Pw = &Ps[wave][0];

    for (int t = 0; t < 4; ++t) {
        {
            const bf* kr = kh + (size_t)(t * 128 + srow) * 64 + sseg;
            bf* kd = Kt + srow * 72 + sseg;
#pragma unroll
            for (int j = 0; j < 4; ++j)
                *(bf16x8*)(kd + j * 8) = *(const bf16x8*)(kr + j * 8);

            const bf* vr = vh + (size_t)(t * 128 + srow) * 64 + sseg;
            bf16x8 vv[4];
#pragma unroll
            for (int j = 0; j < 4; ++j) vv[j] = *(const bf16x8*)(vr + j * 8);
#pragma unroll
            for (int j = 0; j < 4; ++j)
#pragma unroll
                for (int e = 0; e < 8; ++e)
                    Vt[(sseg + j * 8 + e) * 136 + srow] = vv[j][e];
        }
        __syncthreads();

#pragma unroll
        for (int c = 0; c < 2; ++c) {
            const int r0 = wave * 32 + c * 16;
            const bf* qp = qh + (size_t)(r0 + lm) * 64 + quad * 8;
            const bf16x8 a0 = *(const bf16x8*)qp;
            const bf16x8 a1 = *(const bf16x8*)(qp + 32);

            f32x4 s[8];
#pragma unroll
            for (int nt = 0; nt < 8; ++nt) {
                const bf16x8 k0 = *(const bf16x8*)(&Kt[(nt * 16 + lm) * 72 + quad * 8]);
                const bf16x8 k1 = *(const bf16x8*)(&Kt[(nt * 16 + lm) * 72 + 32 + quad * 8]);
                f32x4 z = {};
                z = MFMA(a0, k0, z);
                s[nt] = MFMA(a1, k1, z);
            }

            for (int ntp = 0; ntp < 4; ++ntp) {
#pragma unroll
                for (int tt = 0; tt < 2; ++tt)
#pragma unroll
                    for (int rr = 0; rr < 4; ++rr) {
                        const float e = __expf(s[ntp * 2 + tt][rr] * 0.125f);
                        sum[c][rr] += e;
                        Pw[(quad * 4 + rr) * 40 + tt * 16 + lm] = (bf)e;
                    }
                const bf16x8 ap = *(const bf16x8*)(&Pw[lm * 40 + quad * 8]);
#pragma unroll
                for (int dt = 0; dt < 4; ++dt) {
                    const bf16x8 bv = *(const bf16x8*)(&Vt[(dt * 16 + lm) * 136 + ntp * 32 + quad * 8]);
                    o[c][dt] = MFMA(ap, bv, o[c][dt]);
                }
            }
        }
        __syncthreads();
    }

#pragma unroll
    for (int c = 0; c < 2; ++c) {
        float inv[4];
#pragma unroll
        for (int rr = 0; rr < 4; ++rr) {
            float sm = sum[c][rr];
            sm += __shfl_xor(sm, 1, 64);
            sm += __shfl_xor(sm, 2, 64);
            sm += __shfl_xor(sm, 4, 64);
            sm += __shfl_xor(sm, 8, 64);
            inv[rr] = 1.0f / sm;
        }
        bf* Xp = X + ((size_t)bt * 256 + qb * 128 + wave * 32 + c * 16) * 512 + h * 64;
#pragma unroll
        for (int dt = 0; dt < 4; ++dt)
#pragma unroll
            for (int rr = 0; rr < 4; ++rr)
                Xp[(size_t)(quad * 4 + rr) * 512 + dt * 16 + lm] = (bf)(o[c][dt][rr] * inv[rr]);
    }
}

extern "C" void kernel_launch(void* const* d_in, const int* in_sizes, int n_in,
                              void* d_out, int out_size, void* d_ws, size_t ws_size,
                              hipStream_t stream)
{
    const float* q   = (const float*)d_in[0];  // (8,8,256,512) fp32
    const float* kv  = (const float*)d_in[1];  // (8,8,512,512) fp32
    const float* Wq  = (const float*)d_in[2];
    const float* bq  = (const float*)d_in[3];
    const float* Wkv = (const float*)d_in[4];
    const float* bkv = (const float*)d_in[5];
    const float* Wm  = (const float*)d_in[6];
    const float* bm  = (const float*)d_in[7];
    float* out = (float*)d_out;

    // ws:   kvb [0,32 MiB) (dead after gemm256)    kvn [32,96 MiB)
    //       X   [0,16 MiB) (written in attn, after kvb dead)
    // d_out: wkvb [0,1 MiB)  (dead after gemm256)
    //        qn   [16,32 MiB) (written by qproj, read by attn, dead before outproj
    //                          rewrites all of d_out with fp32 out)
    char* ws = (char*)d_ws;
    bf* kvb = (bf*)ws;
    bf* kvn = (bf*)(ws + ((size_t)32 << 20));
    bf* X   = (bf*)ws;
    char* dob = (char*)d_out;
    bf* wkvb = (bf*)dob;
    bf* qn   = (bf*)(dob + ((size_t)16 << 20));

    {
        auto k0 = gemm256<16, 9>;
        (void)hipFuncSetAttribute((const void*)k0, hipFuncAttributeMaxDynamicSharedMemorySize, 131072);
    }

    // 1. kv + Wkv -> bf16 (kvb written immediately before its consumer)
    cvt2<<<dim3(8448), 256, 0, stream>>>(kv, kvb, 2097152, Wkv, wkvb, 65536);
    // 2. KV projection + bias + L2-norm -> head-major kvn  [R1-exact 8-phase 256^2]
    gemm256<16, 9><<<dim3(128, 4), 512, 131072, stream>>>(kvb, wkvb, bkv, kvn, 32768, 1024, 512);
    // 3. Q projection from pure fp32 inputs (staged converts; no cvt pass for q/Wq)
    qproj<<<dim3(128, 4), 256, 0, stream>>>(q, Wq, bq, qn);
    // 4. no-max flash cosine attention
    attn<<<dim3(1024), 256, 0, stream>>>(qn, kvn, X);
    // 5. output projection + bias + fp32 residual -> fp32 out (Wm staged from fp32)
    outproj<<<dim3(128, 4), 256, 0, stream>>>(X, Wm, bm, q, out);
}

// Round 7
// 280.437 us; speedup vs baseline: 2.1314x; 1.0508x over previous
//
#include <hip/hip_runtime.h>
#include <hip/hip_bf16.h>

using bf = __bf16;
typedef __attribute__((ext_vector_type(8))) __bf16 bf16x8;
typedef __attribute__((ext_vector_type(4))) float f32x4;

#define MFMA(a, b, c) __builtin_amdgcn_mfma_f32_16x16x32_bf16((a), (b), (c), 0, 0, 0)
#define GLL16(g, s)                                                         \
    __builtin_amdgcn_global_load_lds(                                       \
        (const __attribute__((address_space(1))) void*)(g),                 \
        (__attribute__((address_space(3))) void*)(s), 16, 0, 0)

// ---------------- fp32 -> bf16 converts (merged, 8 elems/thread) ----------------
static __device__ __forceinline__ void cvt_one(const float* __restrict__ s,
                                               bf* __restrict__ d, int i)
{
    const f32x4 a = ((const f32x4*)s)[2 * i];
    const f32x4 b = ((const f32x4*)s)[2 * i + 1];
    bf16x8 r;
#pragma unroll
    for (int k = 0; k < 4; ++k) { r[k] = (bf)a[k]; r[4 + k] = (bf)b[k]; }
    ((bf16x8*)d)[i] = r;
}

__global__ __launch_bounds__(256) void cvt2(const float* __restrict__ s1, bf* __restrict__ d1, int n1,
                                            const float* __restrict__ s2, bf* __restrict__ d2, int n2)
{
    int i = blockIdx.x * 256 + threadIdx.x;
    if (i < n1) { cvt_one(s1, d1, i); return; }
    i -= n1;
    if (i < n2) cvt_one(s2, d2, i);
}

__global__ __launch_bounds__(256) void cvt3(const float* __restrict__ s1, bf* __restrict__ d1, int n1,
                                            const float* __restrict__ s2, bf* __restrict__ d2, int n2,
                                            const float* __restrict__ s3, bf* __restrict__ d3, int n3)
{
    int i = blockIdx.x * 256 + threadIdx.x;
    if (i < n1) { cvt_one(s1, d1, i); return; }
    i -= n1;
    if (i < n2) { cvt_one(s2, d2, i); return; }
    i -= n2;
    if (i < n3) cvt_one(s3, d3, i);
}

// ---------------- m97-style bf16 128x128 GEMM (R0-exact) ----------------
// EPI 0: bias + L2-norm per 64-col head group, bf16 head-major out.
// EPI 1: bias + fp32 residual, fp32 out row-major.
template <int EPI, int GH, int LGR>
__global__ __launch_bounds__(256) void gemm128(
    const bf* __restrict__ A, const bf* __restrict__ W,
    const float* __restrict__ bias, const float* __restrict__ res,
    void* __restrict__ Cout, int M, int N, int K)
{
    __shared__ __attribute__((aligned(16))) bf As[128 * 32];
    __shared__ __attribute__((aligned(16))) bf Bs[128 * 32];

    const int lane = threadIdx.x & 63;
    const int wave = threadIdx.x >> 6;
    const int lm = lane & 15;
    const int quad = lane >> 4;
    const int row0 = blockIdx.x * 128, col0 = blockIdx.y * 128;
    const int wrow = (wave >> 1) * 64, wcol = (wave & 1) * 64;

    const int sr = lane >> 2;            // 0..15
    const int sc = (lane & 3) * 8;       // elem offset 0,8,16,24
    const bf* Ag = A + (size_t)(row0 + wave * 32 + sr) * K + sc;
    const bf* Wg = W + (size_t)(col0 + wave * 32 + sr) * K + sc;
    bf* AsW = As + wave * 1024;
    bf* BsW = Bs + wave * 1024;

    f32x4 acc[4][4] = {};

    for (int k0 = 0; k0 < K; k0 += 32) {
        GLL16(Ag + k0, AsW);
        GLL16(Ag + (size_t)16 * K + k0, AsW + 512);
        GLL16(Wg + k0, BsW);
        GLL16(Wg + (size_t)16 * K + k0, BsW + 512);
        __syncthreads();

        bf16x8 a[4], b[4];
#pragma unroll
        for (int i = 0; i < 4; ++i)
            a[i] = *(const bf16x8*)(As + (wrow + i * 16 + lm) * 32 + quad * 8);
#pragma unroll
        for (int j = 0; j < 4; ++j)
            b[j] = *(const bf16x8*)(Bs + (wcol + j * 16 + lm) * 32 + quad * 8);
#pragma unroll
        for (int i = 0; i < 4; ++i)
#pragma unroll
            for (int j = 0; j < 4; ++j)
                acc[i][j] = MFMA(a[i], b[j], acc[i][j]);
        __syncthreads();
    }

    float bv[4];
#pragma unroll
    for (int j = 0; j < 4; ++j) bv[j] = bias[col0 + wcol + j * 16 + lm];

    if (EPI == 0) {
        bf* C = (bf*)Cout;
        const int g = (col0 + wcol) >> 6;
#pragma unroll
        for (int i = 0; i < 4; ++i) {
#pragma unroll
            for (int rg = 0; rg < 4; ++rg) {
                float v[4];
                float ss = 0.f;
#pragma unroll
                for (int j = 0; j < 4; ++j) {
                    const float x = acc[i][j][rg] + bv[j];
                    v[j] = x;
                    ss += x * x;
                }
                ss += __shfl_xor(ss, 1, 64);
                ss += __shfl_xor(ss, 2, 64);
                ss += __shfl_xor(ss, 4, 64);
                ss += __shfl_xor(ss, 8, 64);
                const float inv = 1.0f / fmaxf(sqrtf(ss), 1e-12f);
                const int row = row0 + wrow + i * 16 + quad * 4 + rg;
                const int bt = row >> LGR;
                const int rl = row & ((1 << LGR) - 1);
                bf* Cr = C + (((size_t)(bt * GH + g) << LGR) + rl) * 64;
#pragma unroll
                for (int j = 0; j < 4; ++j)
                    Cr[j * 16 + lm] = (bf)(v[j] * inv);
            }
        }
    } else {
        float* C = (float*)Cout;
#pragma unroll
        for (int i = 0; i < 4; ++i) {
#pragma unroll
            for (int rg = 0; rg < 4; ++rg) {
                const int row = row0 + wrow + i * 16 + quad * 4 + rg;
#pragma unroll
                for (int j = 0; j < 4; ++j) {
                    const size_t idx = (size_t)row * N + col0 + wcol + j * 16 + lm;
                    C[idx] = acc[i][j][rg] + bv[j] + res[idx];
                }
            }
        }
    }
}

// ---------------- 256x256 8-phase bf16 GEMM (R1/R6-verified, 56.4-56.8 us @ KV shape) ----------
// A bf16 + B bf16 via global_load_lds, pre-swizzled sources.  T2 swizzle + counted vmcnt + setprio.
// Epilogue: bias + per-64-col-head L2-norm, bf16 head-major out.
template <int GH, int LGR>
__global__ __launch_bounds__(512, 2) void gemm256(
    const bf* __restrict__ A, const bf* __restrict__ W,
    const float* __restrict__ bias, bf* __restrict__ C,
    int M, int N, int K)
{
    extern __shared__ __attribute__((aligned(16))) char smem[];
    char* Asm = smem;                // [2 buf][2 half][16384 B]
    char* Bsm = smem + 65536;

    const int tid = threadIdx.x;
    const int lane = tid & 63;
    const int lm = lane & 15;
    const int quad = lane >> 4;
    const int wave = tid >> 6;
    const int wm = wave >> 2;        // 0..1  (A half)
    const int wn = wave & 3;         // 0..3
    const int row0 = blockIdx.x * 256, col0 = blockIdx.y * 256;
    const int NT = K >> 6;           // K multiple of 128

    // staging: thread t covers row (t>>3), phys slot (t&7); source slot pre-swizzled
    const int trow = tid >> 3;
    const int tslot = (tid & 7) ^ (trow & 7);
    const bf* Ath = A + (size_t)(row0 + trow) * K + tslot * 8;
    const bf* Wth = W + (size_t)(col0 + trow) * K + tslot * 8;

    // compute-side read bases + swizzled k-slot offsets
    const char* aBase = Asm + wm * 16384 + lm * 128;
    const char* bBase = Bsm + (wn >> 1) * 16384 + ((wn & 1) * 64 + lm) * 128;
    const int skz0 = ((quad ^ (lm & 7)) << 4);
    const int skz1 = (((4 + quad) ^ (lm & 7)) << 4);

    f32x4 acc[8][4] = {};

    auto stA = [&](int kt) {
        const int bo = (kt & 1) * 32768;
#pragma unroll
        for (int h = 0; h < 2; ++h)
#pragma unroll
            for (int s = 0; s < 2; ++s)
                GLL16(Ath + (size_t)(h * 128 + s * 64) * K + kt * 64,
                      Asm + bo + h * 16384 + s * 8192 + tid * 16);
    };
    auto stB = [&](int kt) {
        const int bo = (kt & 1) * 32768;
#pragma unroll
        for (int h = 0; h < 2; ++h)
#pragma unroll
            for (int s = 0; s < 2; ++s)
                GLL16(Wth + (size_t)(h * 128 + s * 64) * K + kt * 64,
                      Bsm + bo + h * 16384 + s * 8192 + tid * 16);
    };

#define LOADA(bo, mh, kk)                                                     \
    _Pragma("unroll")                                                         \
    for (int mm = 0; mm < 4; ++mm)                                            \
        a[mm] = *(const bf16x8*)(aBase + (bo) + ((mh) * 4 + mm) * 2048        \
                                 + ((kk) ? skz1 : skz0));
#define LOADB(bo, kk)                                                         \
    _Pragma("unroll")                                                         \
    for (int j = 0; j < 4; ++j)                                               \
        b[j] = *(const bf16x8*)(bBase + (bo) + j * 2048                       \
                                + ((kk) ? skz1 : skz0));
#define PH_OPEN()                                                             \
    __builtin_amdgcn_s_barrier();                                             \
    asm volatile("s_waitcnt lgkmcnt(0)" ::: "memory");                        \
    __builtin_amdgcn_s_setprio(1)
#define MM16(mh)                                                              \
    _Pragma("unroll")                                                         \
    for (int mm = 0; mm < 4; ++mm)                                            \
        _Pragma("unroll")                                                     \
        for (int j = 0; j < 4; ++j)                                           \
            acc[(mh) * 4 + mm][j] = MFMA(a[mm], b[j], acc[(mh) * 4 + mm][j]);
#define PH_CLOSE()                                                            \
    __builtin_amdgcn_s_setprio(0);                                            \
    __builtin_amdgcn_s_barrier()

    // prologue: stage B0, A0, B1; wait for tile0 (B1 may stay in flight)
    stB(0); stA(0); stB(1);
    asm volatile("s_waitcnt vmcnt(4)" ::: "memory");
    __builtin_amdgcn_s_barrier();

    for (int it = 0; it < NT; it += 2) {
        const int more = (it + 2 < NT);
        bf16x8 a[4], b[4];

        // ---- tile it (buf0) ----
        LOADA(0, 0, 0) LOADB(0, 0) stA(it + 1);
        PH_OPEN(); MM16(0) PH_CLOSE();

        LOADA(0, 1, 0)
        PH_OPEN(); MM16(1) PH_CLOSE();

        LOADA(0, 0, 1) LOADB(0, 1)
        PH_OPEN(); MM16(0) PH_CLOSE();

        LOADA(0, 1, 1) if (more) stB(it + 2);
        PH_OPEN(); MM16(1)
        __builtin_amdgcn_s_setprio(0);
        if (more) { asm volatile("s_waitcnt vmcnt(4)" ::: "memory"); }
        else      { asm volatile("s_waitcnt vmcnt(0)" ::: "memory"); }
        __builtin_amdgcn_s_barrier();

        // ---- tile it+1 (buf1) ----
        LOADA(32768, 0, 0) LOADB(32768, 0) if (more) stA(it + 2);
        PH_OPEN(); MM16(0) PH_CLOSE();

        LOADA(32768, 1, 0)
        PH_OPEN(); MM16(1) PH_CLOSE();

        LOADA(32768, 0, 1) LOADB(32768, 1)
        PH_OPEN(); MM16(0) PH_CLOSE();

        LOADA(32768, 1, 1) if (more) stB(it + 3);
        PH_OPEN(); MM16(1)
        __builtin_amdgcn_s_setprio(0);
        if (more) { asm volatile("s_waitcnt vmcnt(4)" ::: "memory"); }
        __builtin_amdgcn_s_barrier();
    }
#undef LOADA
#undef LOADB
#undef PH_OPEN
#undef MM16
#undef PH_CLOSE

    // ---- epilogue: bias + L2-norm per 64-col head, head-major bf16 out ----
    float bv[4];
#pragma unroll
    for (int j = 0; j < 4; ++j) bv[j] = bias[col0 + wn * 64 + j * 16 + lm];
    const int g = (col0 + wn * 64) >> 6;
#pragma unroll
    for (int m = 0; m < 8; ++m) {
#pragma unroll
        for (int rg = 0; rg < 4; ++rg) {
            float v[4];
            float ss = 0.f;
#pragma unroll
            for (int j = 0; j < 4; ++j) {
                const float x = acc[m][j][rg] + bv[j];
                v[j] = x;
                ss += x * x;
            }
            ss += __shfl_xor(ss, 1, 64);
            ss += __shfl_xor(ss, 2, 64);
            ss += __shfl_xor(ss, 4, 64);
            ss += __shfl_xor(ss, 8, 64);
            const float inv = 1.0f / fmaxf(sqrtf(ss), 1e-12f);
            const int row = row0 + wm * 128 + m * 16 + quad * 4 + rg;
            const int bt = row >> LGR;
            const int rl = row & ((1 << LGR) - 1);
            bf* Cr = C + (((size_t)(bt * GH + g) << LGR) + rl) * 64;
#pragma unroll
            for (int j = 0; j < 4; ++j)
                Cr[j * 16 + lm] = (bf)(v[j] * inv);
        }
    }
}

// ---------------- flash-style cosine attention, NO-MAX softmax (R0-exact) ----------------
__global__ __launch_bounds__(256, 4) void attn(
    const bf* __restrict__ qn, const bf* __restrict__ kvn, bf* __restrict__ X)
{
    __shared__ __attribute__((aligned(16))) bf Kt[128 * 72];
    __shared__ __attribute__((aligned(16))) bf Vt[64 * 136];
    __shared__ __attribute__((aligned(16))) bf Ps[4][16 * 40];

    const int qb = blockIdx.x >> 9;
    const int rb = blockIdx.x & 511;
    const int bt = rb >> 3;
    const int h = rb & 7;
    const int tid = threadIdx.x;
    const int lane = tid & 63;
    const int wave = tid >> 6;
    const int lm = lane & 15;
    const int quad = lane >> 4;

    const bf* qh = qn + ((size_t)(bt * 8 + h) * 256 + qb * 128) * 64;
    const bf* kh = kvn + (size_t)(bt * 16 + h) * 512 * 64;
    const bf* vh = kvn + (size_t)(bt * 16 + 8 + h) * 512 * 64;

    const int srow = tid >> 1;
    const int sseg = (tid & 1) * 32;

    f32x4 o[2][4] = {};
    float sum[2][4] = {};
    bf* Pw = &Ps[wave][0];

    for (int t = 0; t < 4; ++t) {
        {
            const bf* kr = kh + (size_t)(t * 128 + srow) * 64 + sseg;
            bf* kd = Kt + srow * 72 + sseg;
#pragma unroll
            for (int j = 0; j < 4; ++j)
                *(bf16x8*)(kd + j * 8) = *(const bf16x8*)(kr + j * 8);

            const bf* vr = vh + (size_t)(t * 128 + srow) * 64 + sseg;
            bf16x8 vv[4];
#pragma unroll
            for (int j = 0; j < 4; ++j) vv[j] = *(const bf16x8*)(vr + j * 8);
#pragma unroll
            for (int j = 0; j < 4; ++j)
#pragma unroll
                for (int e = 0; e < 8; ++e)
                    Vt[(sseg + j * 8 + e) * 136 + srow] = vv[j][e];
        }
        __syncthreads();

#pragma unroll
        for (int c = 0; c < 2; ++c) {
            const int r0 = wave * 32 + c * 16;
            const bf* qp = qh + (size_t)(r0 + lm) * 64 + quad * 8;
            const bf16x8 a0 = *(const bf16x8*)qp;
            const bf16x8 a1 = *(const bf16x8*)(qp + 32);

            f32x4 s[8];
#pragma unroll
            for (int nt = 0; nt < 8; ++nt) {
                const bf16x8 k0 = *(const bf16x8*)(&Kt[(nt * 16 + lm) * 72 + quad * 8]);
                const bf16x8 k1 = *(const bf16x8*)(&Kt[(nt * 16 + lm) * 72 + 32 + quad * 8]);
                f32x4 z = {};
                z = MFMA(a0, k0, z);
                s[nt] = MFMA(a1, k1, z);
            }

            for (int ntp = 0; ntp < 4; ++ntp) {
#pragma unroll
                for (int tt = 0; tt < 2; ++tt)
#pragma unroll
                    for (int rr = 0; rr < 4; ++rr) {
                        const float e = __expf(s[ntp * 2 + tt][rr] * 0.125f);
                        sum[c][rr] += e;
                        Pw[(quad * 4 + rr) * 40 + tt * 16 + lm] = (bf)e;
                    }
                const bf16x8 ap = *(const bf16x8*)(&Pw[lm * 40 + quad * 8]);
#pragma unroll
                for (int dt = 0; dt < 4; ++dt) {
                    const bf16x8 bv = *(const bf16x8*)(&Vt[(dt * 16 + lm) * 136 + ntp * 32 + quad * 8]);
                    o[c][dt] = MFMA(ap, bv, o[c][dt]);
                }
            }
        }
        __syncthreads();
    }

#pragma unroll
    for (int c = 0; c < 2; ++c) {
        float inv[4];
#pragma unroll
        for (int rr = 0; rr < 4; ++rr) {
            float sm = sum[c][rr];
            sm += __shfl_xor(sm, 1, 64);
            sm += __shfl_xor(sm, 2, 64);
            sm += __shfl_xor(sm, 4, 64);
            sm += __shfl_xor(sm, 8, 64);
            inv[rr] = 1.0f / sm;
        }
        bf* Xp = X + ((size_t)bt * 256 + qb * 128 + wave * 32 + c * 16) * 512 + h * 64;
#pragma unroll
        for (int dt = 0; dt < 4; ++dt)
#pragma unroll
            for (int rr = 0; rr < 4; ++rr)
                Xp[(size_t)(quad * 4 + rr) * 512 + dt * 16 + lm] = (bf)(o[c][dt][rr] * inv[rr]);
    }
}

extern "C" void kernel_launch(void* const* d_in, const int* in_sizes, int n_in,
                              void* d_out, int out_size, void* d_ws, size_t ws_size,
                              hipStream_t stream)
{
    const float* q   = (const float*)d_in[0];  // (8,8,256,512) fp32
    const float* kv  = (const float*)d_in[1];  // (8,8,512,512) fp32
    const float* Wq  = (const float*)d_in[2];  // (512,512) fp32
    const float* bq  = (const float*)d_in[3];  // (512) fp32
    const float* Wkv = (const float*)d_in[4];  // (1024,512) fp32
    const float* bkv = (const float*)d_in[5];  // (1024) fp32
    const float* Wm  = (const float*)d_in[6];  // (512,512) fp32
    const float* bm  = (const float*)d_in[7];  // (512) fp32
    float* out = (float*)d_out;                // (8,8,256,512) fp32 (32 MiB)

    // R0-exact buffer map:
    // ws:   kvb [0,32 MiB) (dead after step 2)      kvn [32,96 MiB)
    //       wqb [0,0.5 MiB) (written step 3, after kvb dead)
    //       wmb [16,16.5 MiB) (written step 3, survives: X is [0,16))
    //       X   [0,16 MiB) (written step 5, after wqb dead)
    // d_out: wkvb [0,1 MiB) (dead after step 2); qb [0,16 MiB) (written step 3);
    //        qn [16,32 MiB); step 6 rewrites all of d_out with fp32 out.
    char* ws = (char*)d_ws;
    bf* kvb = (bf*)ws;
    bf* kvn = (bf*)(ws + (size_t)(32 << 20));
    bf* wqb = (bf*)ws;
    bf* wmb = (bf*)(ws + (size_t)(16 << 20));
    bf* X   = (bf*)ws;
    char* dob = (char*)d_out;
    bf* wkvb = (bf*)dob;
    bf* qb   = (bf*)dob;
    bf* qn   = (bf*)(dob + (size_t)(16 << 20));

    {
        auto k0 = gemm256<16, 9>;
        (void)hipFuncSetAttribute((const void*)k0, hipFuncAttributeMaxDynamicSharedMemorySize, 131072);
    }

    // 1. kv + Wkv -> bf16
    cvt2<<<dim3(8448), 256, 0, stream>>>(kv, kvb, 2097152, Wkv, wkvb, 65536);
    // 2. KV projection + bias + fused L2-norm -> head-major kvn  [verified 8-phase 256^2, 56.6 us]
    gemm256<16, 9><<<dim3(128, 4), 512, 131072, stream>>>(kvb, wkvb, bkv, kvn, 32768, 1024, 512);
    // 3. q, Wq, Wm -> bf16
    cvt3<<<dim3(4352), 256, 0, stream>>>(q, qb, 1048576, Wq, wqb, 32768, Wm, wmb, 32768);
    // 4. Q projection + bias + fused L2-norm -> head-major qn  [R0-exact gemm128]
    gemm128<0, 8, 8><<<dim3(128, 4), 256, 0, stream>>>(qb, wqb, bq, nullptr, qn, 16384, 512, 512);
    // 5. no-max flash cosine attention  [R0-exact]
    attn<<<dim3(1024), 256, 0, stream>>>(qn, kvn, X);
    // 6. output projection + bias + fp32 residual -> fp32 out  [R0-exact gemm128]
    gemm128<1, 0, 0><<<dim3(128, 4), 256, 0, stream>>>(X, wmb, bm, q, out, 16384, 512, 512);
}